// Round 1
// baseline (605.670 us; speedup 1.0000x reference)
//
#include <hip/hip_runtime.h>
#include <math.h>

#define LVL 4
#define NN 65536
#define DD 512
#define NBLK 256                 // partial-sum blocks per level
#define ROWS_PER_BLK (NN / NBLK) // 256
#define LN_EPS 1e-5f
#define ATTN_SCALE 0.08838834764831845f  // (512/4)^-0.5

// ws layout (floats)
#define WS_PARTIALS 0                        // LVL*NBLK*DD = 524288
#define WS_SUMM (WS_PARTIALS + LVL*NBLK*DD)  // LVL*DD
#define WS_QKV  (WS_SUMM + LVL*DD)           // 3*LVL*DD (q,k,v)
#define WS_CTX  (WS_QKV + 3*LVL*DD)          // LVL*DD
#define WS_H    (WS_CTX + LVL*DD)            // LVL*DD
#define WS_UPD  (WS_H + LVL*DD)              // LVL*DD

// ---------------- K1: partial column sums of x over N ----------------
__global__ __launch_bounds__(256) void colsum_kernel(const float* __restrict__ x,
                                                     float* __restrict__ partials) {
    int blk = blockIdx.x;            // 0 .. LVL*NBLK-1
    int l = blk / NBLK;
    int b = blk % NBLK;
    int t = threadIdx.x;             // 256
    int lane = t & 127;              // covers DD/4 = 128 float4 per row
    int rg = t >> 7;                 // 2 row groups
    const float4* xp = (const float4*)(x + ((size_t)l * NN + (size_t)b * ROWS_PER_BLK) * DD);
    float4 acc = make_float4(0.f, 0.f, 0.f, 0.f);
    for (int i = 0; i < ROWS_PER_BLK / 2; ++i) {
        int row = i * 2 + rg;
        float4 v = xp[(size_t)row * (DD / 4) + lane];
        acc.x += v.x; acc.y += v.y; acc.z += v.z; acc.w += v.w;
    }
    __shared__ float4 red[128];
    if (rg == 1) red[lane] = acc;
    __syncthreads();
    if (rg == 0) {
        float4 o = red[lane];
        acc.x += o.x; acc.y += o.y; acc.z += o.z; acc.w += o.w;
        ((float4*)(partials + (size_t)(l * NBLK + b) * DD))[lane] = acc;
    }
}

// ---------------- K2: reduce partials -> summ (mean) ----------------
__global__ __launch_bounds__(256) void reduce_summ_kernel(const float* __restrict__ partials,
                                                          float* __restrict__ summ) {
    int idx = blockIdx.x * 256 + threadIdx.x;  // 0 .. LVL*DD-1
    int l = idx / DD, d = idx % DD;
    const float* p = partials + (size_t)l * NBLK * DD + d;
    float s = 0.f;
    for (int b = 0; b < NBLK; ++b) s += p[(size_t)b * DD];
    summ[idx] = s * (1.0f / NN);
}

// ---------------- generic per-level matvec: out[l,e] = act(sum_d in[l,d]*W[l,d,e] + bias[l,e]) ----
__global__ __launch_bounds__(256) void matvec_kernel(const float* __restrict__ in,
                                                     const float* __restrict__ W,
                                                     const float* __restrict__ bias,
                                                     float* __restrict__ out, int relu) {
    int blk = blockIdx.x;            // LVL * (DD/64) blocks
    int ec = blk % (DD / 64);
    int l  = blk / (DD / 64);
    int t = threadIdx.x;
    int e = ec * 64 + (t & 63);
    int dg = t >> 6;                 // 0..3
    const float* iv = in + (size_t)l * DD;
    const float* Wl = W + (size_t)l * DD * DD;
    float acc = 0.f;
    for (int d = dg * 128; d < dg * 128 + 128; ++d)
        acc += iv[d] * Wl[(size_t)d * DD + e];
    __shared__ float red[256];
    red[t] = acc;
    __syncthreads();
    if (t < 128) red[t] += red[t + 128];
    __syncthreads();
    if (t < 64) {
        float r = red[t] + red[t + 64] + bias[(size_t)l * DD + e];
        if (relu) r = fmaxf(r, 0.f);
        out[(size_t)l * DD + e] = r;
    }
}

// ---------------- K4: scores + masked softmax + ctx (one block) ----------------
__global__ __launch_bounds__(256) void attn_kernel(const float* __restrict__ qkv,
                                                   float* __restrict__ ctx) {
    __shared__ float sq[LVL * DD], sk[LVL * DD], sv[LVL * DD];
    __shared__ float at[LVL * LVL];
    __shared__ float sc[LVL * LVL];
    int t = threadIdx.x;
    for (int i = t; i < LVL * DD; i += 256) {
        sq[i] = qkv[i];
        sk[i] = qkv[LVL * DD + i];
        sv[i] = qkv[2 * LVL * DD + i];
    }
    __syncthreads();
    // 16 (i,j) pairs, 16 lanes each
    int p = t >> 4, lane = t & 15;
    int i = p >> 2, j = p & 3;
    float acc = 0.f;
    for (int d = lane; d < DD; d += 16)
        acc += sq[i * DD + d] * sk[j * DD + d];
    for (int off = 8; off >= 1; off >>= 1)
        acc += __shfl_down(acc, off, 16);
    if (lane == 0) sc[p] = acc * ATTN_SCALE;
    __syncthreads();
    if (t < LVL) {
        float row[LVL];
        float m = -1e30f;
        for (int jj = 0; jj < LVL; ++jj) {
            row[jj] = (jj == t) ? -1e30f : sc[t * LVL + jj];
            m = fmaxf(m, row[jj]);
        }
        float ssum = 0.f;
        for (int jj = 0; jj < LVL; ++jj) { row[jj] = expf(row[jj] - m); ssum += row[jj]; }
        float inv = 1.0f / ssum;
        for (int jj = 0; jj < LVL; ++jj) at[t * LVL + jj] = row[jj] * inv;
    }
    __syncthreads();
    for (int o = t; o < LVL * DD; o += 256) {
        int ii = o >> 9, e = o & (DD - 1);
        float a = 0.f;
        for (int jj = 0; jj < LVL; ++jj) a += at[ii * LVL + jj] * sv[jj * DD + e];
        ctx[o] = a;
    }
}

// ---------------- K7: fused residual add + LayerNorm ----------------
__global__ __launch_bounds__(256) void final_ln_kernel(const float* __restrict__ x,
                                                       const float* __restrict__ upd,
                                                       const float* __restrict__ gamma,
                                                       const float* __restrict__ beta,
                                                       float* __restrict__ out) {
    int wid = (blockIdx.x * blockDim.x + threadIdx.x) >> 6;
    int lane = threadIdx.x & 63;
    int nw = (gridDim.x * blockDim.x) >> 6;
    const long long totalRows = (long long)LVL * NN;
    for (long long r = wid; r < totalRows; r += nw) {
        int l = (int)(r >> 16);  // NN = 65536
        const float4* xr = (const float4*)(x + r * DD);
        // lane covers dims [lane*4, lane*4+4) and [256 + lane*4, 256 + lane*4 + 4)
        float4 a = xr[lane];
        float4 b = xr[64 + lane];
        const float4* ur = (const float4*)(upd + (size_t)l * DD);
        float4 ua = ur[lane], ub = ur[64 + lane];
        a.x += ua.x; a.y += ua.y; a.z += ua.z; a.w += ua.w;
        b.x += ub.x; b.y += ub.y; b.z += ub.z; b.w += ub.w;
        float s  = a.x + a.y + a.z + a.w + b.x + b.y + b.z + b.w;
        float sq = a.x * a.x + a.y * a.y + a.z * a.z + a.w * a.w
                 + b.x * b.x + b.y * b.y + b.z * b.z + b.w * b.w;
        for (int off = 32; off >= 1; off >>= 1) {
            s  += __shfl_down(s, off);
            sq += __shfl_down(sq, off);
        }
        s = __shfl(s, 0);
        sq = __shfl(sq, 0);
        float mu = s * (1.0f / DD);
        float var = sq * (1.0f / DD) - mu * mu;
        float inv = rsqrtf(var + LN_EPS);
        const float4* gr = (const float4*)(gamma + (size_t)l * DD);
        const float4* br = (const float4*)(beta + (size_t)l * DD);
        float4 g0 = gr[lane], g1 = gr[64 + lane];
        float4 bb0 = br[lane], bb1 = br[64 + lane];
        float4 o0, o1;
        o0.x = (a.x - mu) * inv * g0.x + bb0.x;
        o0.y = (a.y - mu) * inv * g0.y + bb0.y;
        o0.z = (a.z - mu) * inv * g0.z + bb0.z;
        o0.w = (a.w - mu) * inv * g0.w + bb0.w;
        o1.x = (b.x - mu) * inv * g1.x + bb1.x;
        o1.y = (b.y - mu) * inv * g1.y + bb1.y;
        o1.z = (b.z - mu) * inv * g1.z + bb1.z;
        o1.w = (b.w - mu) * inv * g1.w + bb1.w;
        float4* orow = (float4*)(out + r * DD);
        orow[lane] = o0;
        orow[64 + lane] = o1;
    }
}

extern "C" void kernel_launch(void* const* d_in, const int* in_sizes, int n_in,
                              void* d_out, int out_size, void* d_ws, size_t ws_size,
                              hipStream_t stream) {
    const float* x     = (const float*)d_in[0];
    const float* Wq    = (const float*)d_in[1];
    const float* bq    = (const float*)d_in[2];
    const float* Wk    = (const float*)d_in[3];
    const float* bk    = (const float*)d_in[4];
    const float* Wv    = (const float*)d_in[5];
    const float* bv    = (const float*)d_in[6];
    const float* W1    = (const float*)d_in[7];
    const float* b1    = (const float*)d_in[8];
    const float* W2    = (const float*)d_in[9];
    const float* b2    = (const float*)d_in[10];
    const float* gamma = (const float*)d_in[11];
    const float* beta  = (const float*)d_in[12];
    float* out = (float*)d_out;
    float* ws = (float*)d_ws;

    float* partials = ws + WS_PARTIALS;
    float* summ     = ws + WS_SUMM;
    float* qkv      = ws + WS_QKV;       // q, k, v contiguous
    float* ctx      = ws + WS_CTX;
    float* h        = ws + WS_H;
    float* upd      = ws + WS_UPD;

    // 1) column sums of x
    colsum_kernel<<<LVL * NBLK, 256, 0, stream>>>(x, partials);
    // 2) reduce -> summ
    reduce_summ_kernel<<<(LVL * DD) / 256, 256, 0, stream>>>(partials, summ);
    // 3) q, k, v projections
    matvec_kernel<<<LVL * (DD / 64), 256, 0, stream>>>(summ, Wq, bq, qkv + 0 * LVL * DD, 0);
    matvec_kernel<<<LVL * (DD / 64), 256, 0, stream>>>(summ, Wk, bk, qkv + 1 * LVL * DD, 0);
    matvec_kernel<<<LVL * (DD / 64), 256, 0, stream>>>(summ, Wv, bv, qkv + 2 * LVL * DD, 0);
    // 4) attention combine
    attn_kernel<<<1, 256, 0, stream>>>(qkv, ctx);
    // 5) MLP
    matvec_kernel<<<LVL * (DD / 64), 256, 0, stream>>>(ctx, W1, b1, h, 1);
    matvec_kernel<<<LVL * (DD / 64), 256, 0, stream>>>(h, W2, b2, upd, 0);
    // 6) fused residual + LayerNorm
    final_ln_kernel<<<2048, 256, 0, stream>>>(x, upd, gamma, beta, out);
}

// Round 2
// 388.273 us; speedup vs baseline: 1.5599x; 1.5599x over previous
//
#include <hip/hip_runtime.h>
#include <math.h>

#define LVL 4
#define NN 65536
#define DD 512
#define NBLK 256                 // partial-sum blocks per level
#define ROWS_PER_BLK (NN / NBLK) // 256
#define LN_EPS 1e-5f
#define ATTN_SCALE 0.08838834764831845f  // (512/4)^-0.5

// ws layout (floats)
#define WS_PARTIALS 0                        // LVL*NBLK*DD = 524288
#define WS_QKV  (WS_PARTIALS + LVL*NBLK*DD)  // 3*LVL*DD (q,k,v)
#define WS_H    (WS_QKV + 3*LVL*DD)          // LVL*DD
#define WS_UPD  (WS_H + LVL*DD)              // LVL*DD

// ---------------- K1: partial column sums of x over N ----------------
__global__ __launch_bounds__(256) void colsum_kernel(const float* __restrict__ x,
                                                     float* __restrict__ partials) {
    int blk = blockIdx.x;            // 0 .. LVL*NBLK-1
    int l = blk / NBLK;
    int b = blk % NBLK;
    int t = threadIdx.x;             // 256
    int lane = t & 127;              // covers DD/4 = 128 float4 per row
    int rg = t >> 7;                 // 2 row groups
    const float4* xp = (const float4*)(x + ((size_t)l * NN + (size_t)b * ROWS_PER_BLK) * DD);
    float4 acc = make_float4(0.f, 0.f, 0.f, 0.f);
    for (int i = 0; i < ROWS_PER_BLK / 2; ++i) {
        int row = i * 2 + rg;
        float4 v = xp[(size_t)row * (DD / 4) + lane];
        acc.x += v.x; acc.y += v.y; acc.z += v.z; acc.w += v.w;
    }
    __shared__ float4 red[128];
    if (rg == 1) red[lane] = acc;
    __syncthreads();
    if (rg == 0) {
        float4 o = red[lane];
        acc.x += o.x; acc.y += o.y; acc.z += o.z; acc.w += o.w;
        ((float4*)(partials + (size_t)(l * NBLK + b) * DD))[lane] = acc;
    }
}

// ---------------- K2: fused summ-reduce + q/k/v matvec ----------------
// grid = 96 blocks: mat = blk>>5 (0=q,1=k,2=v), sub = blk&31: l = sub>>3, ec = sub&7
__global__ __launch_bounds__(1024) void qkv_kernel(const float* __restrict__ partials,
                                                   const float* __restrict__ Wq,
                                                   const float* __restrict__ bq,
                                                   const float* __restrict__ Wk,
                                                   const float* __restrict__ bk,
                                                   const float* __restrict__ Wv,
                                                   const float* __restrict__ bv,
                                                   float* __restrict__ qkv) {
    int blk = blockIdx.x;
    int mat = blk >> 5;
    int sub = blk & 31;
    int l = sub >> 3, ec = sub & 7;
    int t = threadIdx.x;
    const float* W    = (mat == 0) ? Wq : (mat == 1) ? Wk : Wv;
    const float* bias = (mat == 0) ? bq : (mat == 1) ? bk : bv;

    __shared__ float summ[DD];
    __shared__ float red[1024];

    // reduce partials[l][0..255][d] -> summ[d] (split b-range over 2 halves)
    {
        int d = t & 511, half = t >> 9;
        const float* p = partials + (size_t)l * NBLK * DD + d;
        float s = 0.f;
        for (int b = half * 128; b < half * 128 + 128; ++b) s += p[(size_t)b * DD];
        if (half) red[d] = s;
        __syncthreads();
        if (!half) summ[d] = (s + red[d]) * (1.0f / NN);
        __syncthreads();
    }

    // matvec: 64 e-cols x 16 d-groups of 32
    int e = t & 63, dg = t >> 6;
    int ecol = ec * 64 + e;
    const float* Wl = W + (size_t)l * DD * DD;
    float acc = 0.f;
    for (int d = dg * 32; d < dg * 32 + 32; ++d)
        acc += summ[d] * Wl[(size_t)d * DD + ecol];
    red[t] = acc;
    __syncthreads();
    for (int s = 512; s >= 64; s >>= 1) {
        if (t < s) red[t] += red[t + s];
        __syncthreads();
    }
    if (t < 64)
        qkv[(size_t)mat * LVL * DD + (size_t)l * DD + ec * 64 + t] =
            red[t] + bias[(size_t)l * DD + ec * 64 + t];
}

// ---------------- K3: fused attention softmax + ctx + W1 matvec (ReLU) ----------------
// grid = 32 blocks: l = blk>>3, ec = blk&7. Each block recomputes the softmax row for l.
__global__ __launch_bounds__(1024) void attn_h_kernel(const float* __restrict__ qkv,
                                                      const float* __restrict__ W1,
                                                      const float* __restrict__ b1,
                                                      float* __restrict__ h) {
    int l = blockIdx.x >> 3, ec = blockIdx.x & 7;
    int t = threadIdx.x;
    const float* q = qkv;
    const float* k = qkv + LVL * DD;
    const float* v = qkv + 2 * LVL * DD;

    __shared__ float red[1024];
    __shared__ float atw[LVL];
    __shared__ float ctx[DD];

    // scores: 4 dots of 512, j = t>>8, dd = t&255 (two elems per thread)
    {
        int j = t >> 8, dd = t & 255;
        float a = q[l * DD + dd] * k[j * DD + dd]
                + q[l * DD + dd + 256] * k[j * DD + dd + 256];
        red[t] = a;
        __syncthreads();
        for (int s = 128; s >= 1; s >>= 1) {
            if ((t & 255) < s) red[t] += red[t + s];
            __syncthreads();
        }
        if (t == 0) {
            float sc[LVL], m = -1e30f;
            for (int jj = 0; jj < LVL; ++jj) {
                sc[jj] = (jj == l) ? -1e30f : red[jj * 256] * ATTN_SCALE;
                m = fmaxf(m, sc[jj]);
            }
            float ssum = 0.f;
            for (int jj = 0; jj < LVL; ++jj) { sc[jj] = expf(sc[jj] - m); ssum += sc[jj]; }
            float inv = 1.0f / ssum;
            for (int jj = 0; jj < LVL; ++jj) atw[jj] = sc[jj] * inv;
        }
        __syncthreads();
    }

    // ctx[d] = sum_j atw[j] * v[j][d]
    if (t < DD) {
        float c = 0.f;
        for (int jj = 0; jj < LVL; ++jj) c += atw[jj] * v[jj * DD + t];
        ctx[t] = c;
    }
    __syncthreads();

    // matvec h = relu(ctx @ W1 + b1)
    int e = t & 63, dg = t >> 6;
    int ecol = ec * 64 + e;
    const float* Wl = W1 + (size_t)l * DD * DD;
    float acc = 0.f;
    for (int d = dg * 32; d < dg * 32 + 32; ++d)
        acc += ctx[d] * Wl[(size_t)d * DD + ecol];
    red[t] = acc;
    __syncthreads();
    for (int s = 512; s >= 64; s >>= 1) {
        if (t < s) red[t] += red[t + s];
        __syncthreads();
    }
    if (t < 64) {
        float r = red[t] + b1[(size_t)l * DD + ec * 64 + t];
        h[(size_t)l * DD + ec * 64 + t] = fmaxf(r, 0.f);
    }
}

// ---------------- K4: upd matvec (in from global, tiny/L2-hot) ----------------
__global__ __launch_bounds__(1024) void matvec1024_kernel(const float* __restrict__ in,
                                                          const float* __restrict__ W,
                                                          const float* __restrict__ bias,
                                                          float* __restrict__ out) {
    int l = blockIdx.x >> 3, ec = blockIdx.x & 7;
    int t = threadIdx.x;
    __shared__ float red[1024];
    int e = t & 63, dg = t >> 6;
    int ecol = ec * 64 + e;
    const float* iv = in + (size_t)l * DD;
    const float* Wl = W + (size_t)l * DD * DD;
    float acc = 0.f;
    for (int d = dg * 32; d < dg * 32 + 32; ++d)
        acc += iv[d] * Wl[(size_t)d * DD + ecol];
    red[t] = acc;
    __syncthreads();
    for (int s = 512; s >= 64; s >>= 1) {
        if (t < s) red[t] += red[t + s];
        __syncthreads();
    }
    if (t < 64)
        out[(size_t)l * DD + ec * 64 + t] = red[t] + bias[(size_t)l * DD + ec * 64 + t];
}

// ---------------- K5: fused residual add + LayerNorm ----------------
__global__ __launch_bounds__(256) void final_ln_kernel(const float* __restrict__ x,
                                                       const float* __restrict__ upd,
                                                       const float* __restrict__ gamma,
                                                       const float* __restrict__ beta,
                                                       float* __restrict__ out) {
    int wid = (blockIdx.x * blockDim.x + threadIdx.x) >> 6;
    int lane = threadIdx.x & 63;
    int nw = (gridDim.x * blockDim.x) >> 6;
    const long long totalRows = (long long)LVL * NN;
    for (long long r = wid; r < totalRows; r += nw) {
        int l = (int)(r >> 16);  // NN = 65536
        const float4* xr = (const float4*)(x + r * DD);
        float4 a = xr[lane];
        float4 b = xr[64 + lane];
        const float4* ur = (const float4*)(upd + (size_t)l * DD);
        float4 ua = ur[lane], ub = ur[64 + lane];
        a.x += ua.x; a.y += ua.y; a.z += ua.z; a.w += ua.w;
        b.x += ub.x; b.y += ub.y; b.z += ub.z; b.w += ub.w;
        float s  = a.x + a.y + a.z + a.w + b.x + b.y + b.z + b.w;
        float sq = a.x * a.x + a.y * a.y + a.z * a.z + a.w * a.w
                 + b.x * b.x + b.y * b.y + b.z * b.z + b.w * b.w;
        for (int off = 32; off >= 1; off >>= 1) {
            s  += __shfl_down(s, off);
            sq += __shfl_down(sq, off);
        }
        s = __shfl(s, 0);
        sq = __shfl(sq, 0);
        float mu = s * (1.0f / DD);
        float var = sq * (1.0f / DD) - mu * mu;
        float inv = rsqrtf(var + LN_EPS);
        const float4* gr = (const float4*)(gamma + (size_t)l * DD);
        const float4* br = (const float4*)(beta + (size_t)l * DD);
        float4 g0 = gr[lane], g1 = gr[64 + lane];
        float4 bb0 = br[lane], bb1 = br[64 + lane];
        float4 o0, o1;
        o0.x = (a.x - mu) * inv * g0.x + bb0.x;
        o0.y = (a.y - mu) * inv * g0.y + bb0.y;
        o0.z = (a.z - mu) * inv * g0.z + bb0.z;
        o0.w = (a.w - mu) * inv * g0.w + bb0.w;
        o1.x = (b.x - mu) * inv * g1.x + bb1.x;
        o1.y = (b.y - mu) * inv * g1.y + bb1.y;
        o1.z = (b.z - mu) * inv * g1.z + bb1.z;
        o1.w = (b.w - mu) * inv * g1.w + bb1.w;
        float4* orow = (float4*)(out + r * DD);
        orow[lane] = o0;
        orow[64 + lane] = o1;
    }
}

extern "C" void kernel_launch(void* const* d_in, const int* in_sizes, int n_in,
                              void* d_out, int out_size, void* d_ws, size_t ws_size,
                              hipStream_t stream) {
    const float* x     = (const float*)d_in[0];
    const float* Wq    = (const float*)d_in[1];
    const float* bq    = (const float*)d_in[2];
    const float* Wk    = (const float*)d_in[3];
    const float* bk    = (const float*)d_in[4];
    const float* Wv    = (const float*)d_in[5];
    const float* bv    = (const float*)d_in[6];
    const float* W1    = (const float*)d_in[7];
    const float* b1    = (const float*)d_in[8];
    const float* W2    = (const float*)d_in[9];
    const float* b2    = (const float*)d_in[10];
    const float* gamma = (const float*)d_in[11];
    const float* beta  = (const float*)d_in[12];
    float* out = (float*)d_out;
    float* ws = (float*)d_ws;

    float* partials = ws + WS_PARTIALS;
    float* qkv      = ws + WS_QKV;
    float* h        = ws + WS_H;
    float* upd      = ws + WS_UPD;

    colsum_kernel<<<LVL * NBLK, 256, 0, stream>>>(x, partials);
    qkv_kernel<<<96, 1024, 0, stream>>>(partials, Wq, bq, Wk, bk, Wv, bv, qkv);
    attn_h_kernel<<<32, 1024, 0, stream>>>(qkv, W1, b1, h);
    matvec1024_kernel<<<32, 1024, 0, stream>>>(h, W2, b2, upd);
    final_ln_kernel<<<2048, 256, 0, stream>>>(x, upd, gamma, beta, out);
}